// Round 6
// baseline (829.979 us; speedup 1.0000x reference)
//
#include <hip/hip_runtime.h>

// Geo_GCN via MSD bucket sort (bucket = row>>6 = one 64-node output tile).
// Eliminates per-edge cursor atomics AND scattered payload stores; the only
// remaining memory-side random writes are the irreducible 1.6M colcnt atomics
// (measured ceiling: ~32B/op @ ~850GB/s on the RMW write path).
//
// Pipeline: hist(+colcnt) -> scan(part/blk/final) -> scatter1(LDS cursors)
//           -> dinv -> gather_acc (LDS accumulator + fused @W^T+b epilogue)

constexpr int NN   = 100000;
constexpr int NE   = 1600000;
constexpr int D    = 64;
constexpr int NBUK = (NN + 63) / 64;        // 1563 buckets of 64 nodes
constexpr int HB   = 256;                   // hist/scatter grid
constexpr int HT   = 1024;                  // hist/scatter block
constexpr int CHUNK = NE / HB;              // 6250 edges/block (exact)
constexpr int NSC  = NBUK * HB;             // 400128 scan elements
constexpr int SCB  = 1024;
constexpr int SCG  = (NSC + SCB - 1) / SCB; // 391 scan blocks

// ---- pass 1: bucket histogram (LDS) + colcnt (global atomics, the floor) ----
__global__ void __launch_bounds__(HT)
hist_kernel(const int* __restrict__ row, const int* __restrict__ col,
            int* __restrict__ colcnt, int* __restrict__ histT) {
    __shared__ int h[NBUK];
    const int t = threadIdx.x;
    for (int i = t; i < NBUK; i += HT) h[i] = 0;
    __syncthreads();
    const int e0 = blockIdx.x * CHUNK;
    for (int e = e0 + t; e < e0 + CHUNK; e += HT) {
        atomicAdd(&h[row[e] >> 6], 1);      // LDS, cheap
        atomicAdd(&colcnt[col[e]], 1);      // global, ~60us total (irreducible)
    }
    __syncthreads();
    for (int i = t; i < NBUK; i += HT) histT[i * HB + blockIdx.x] = h[i];
}

// ---- scan over histT[NSC] (flat (bucket,block) order) ----
__global__ void scanpart_kernel(const int* __restrict__ a, int* __restrict__ bsum) {
    __shared__ int red[16];
    const int t = threadIdx.x;
    const int i = blockIdx.x * SCB + t;
    int v = (i < NSC) ? a[i] : 0;
    int s = v;
    #pragma unroll
    for (int o = 1; o < 64; o <<= 1) s += __shfl_xor(s, o);
    if ((t & 63) == 0) red[t >> 6] = s;
    __syncthreads();
    if (t < 16) {
        int ss = red[t];
        #pragma unroll
        for (int o = 1; o < 16; o <<= 1) ss += __shfl_xor(ss, o);
        if (t == 0) bsum[blockIdx.x] = ss;
    }
}

__global__ void scanblk_kernel(const int* __restrict__ bsum, int* __restrict__ boff) {
    __shared__ int wsum[8], wsum2[8];
    const int t = threadIdx.x;          // 512
    const int lane = t & 63;
    const int w = t >> 6;               // 0..7
    const int v = (t < SCG) ? bsum[t] : 0;
    int s = v;
    #pragma unroll
    for (int o = 1; o < 64; o <<= 1) { int u = __shfl_up(s, o); if (lane >= o) s += u; }
    if (lane == 63) wsum[w] = s;
    __syncthreads();
    if (t < 8) {
        int ss = wsum[t];
        #pragma unroll
        for (int o = 1; o < 8; o <<= 1) { int u = __shfl_up(ss, o); if (t >= o) ss += u; }
        wsum2[t] = ss;
    }
    __syncthreads();
    const int excl = (w ? wsum2[w - 1] : 0) + (s - v);
    if (t < SCG) boff[t] = excl;
}

__global__ void scanfinal_kernel(const int* __restrict__ a, const int* __restrict__ boff,
                                 int* __restrict__ hoff) {
    __shared__ int wsum[16], wsum2[16];
    const int t = threadIdx.x;
    const int i = blockIdx.x * SCB + t;
    const int lane = t & 63;
    const int w = t >> 6;
    const int v = (i < NSC) ? a[i] : 0;
    int s = v;
    #pragma unroll
    for (int o = 1; o < 64; o <<= 1) { int u = __shfl_up(s, o); if (lane >= o) s += u; }
    if (lane == 63) wsum[w] = s;
    __syncthreads();
    if (t < 16) {
        int ss = wsum[t];
        #pragma unroll
        for (int o = 1; o < 16; o <<= 1) { int u = __shfl_up(ss, o); if (t >= o) ss += u; }
        wsum2[t] = ss;
    }
    __syncthreads();
    const int excl = boff[blockIdx.x] + (w ? wsum2[w - 1] : 0) + (s - v);
    if (i < NSC) hoff[i] = excl;
}

// ---- pass 2: place edges into buckets via LDS cursors (no global atomics) ----
__global__ void __launch_bounds__(HT)
scatter1_kernel(const int* __restrict__ row, const int* __restrict__ col,
                const float* __restrict__ dist, const int* __restrict__ hoff,
                int2* __restrict__ edges8) {
    __shared__ int cur[NBUK];
    const int t = threadIdx.x;
    for (int i = t; i < NBUK; i += HT) cur[i] = hoff[i * HB + blockIdx.x];
    __syncthreads();
    const int e0 = blockIdx.x * CHUNK;
    for (int e = e0 + t; e < e0 + CHUNK; e += HT) {
        const int r = row[e];
        const int c = col[e];
        const float dv = dist[e];
        const float wv = expf(-dv * dv);                         // (e^-1, 1]
        const unsigned w15 = (unsigned)(wv * 32767.0f + 0.5f);   // 15-bit fixed pt
        const int pos = atomicAdd(&cur[r >> 6], 1);              // LDS atomic
        edges8[pos] = make_int2((int)((w15 << 17) | (unsigned)c), r);
    }
}

// ---- dinv = colcnt^{-1/2} ----
__global__ void dinv_kernel(const int* __restrict__ colcnt, float* __restrict__ dinv) {
    int i = blockIdx.x * blockDim.x + threadIdx.x;
    if (i < NN) {
        const int d = colcnt[i];
        dinv[i] = (d > 0) ? rsqrtf((float)d) : 0.0f;
    }
}

// ---- pass 3: per-bucket gather into LDS accumulator + fused epilogue GEMM ----
// Block = one bucket (64 nodes). Per edge: whole wave (lane=channel) does
// acc[r&63][lane] += w*dinv[c]*x[c][lane] via ds_add_f32 (2-way bank = free).
// Epilogue: out[n] = b + dinv[n] * (acc[n] . W[j]) with float4 LDS reads;
// Ws padded to 68 floats/row -> granule stride 17 (odd) -> conflict-free b128.
__global__ void __launch_bounds__(256)
gather_acc_kernel(const int* __restrict__ hoff, const int2* __restrict__ edges8,
                  const float* __restrict__ dinvg, const float* __restrict__ x,
                  const float* __restrict__ W, const float* __restrict__ bias,
                  float* __restrict__ out) {
    __shared__ float acc[64][64];   // 16KB accumulator (node x channel)
    __shared__ float Ws[64][68];    // W rows, padded
    __shared__ float bs[64];
    const int t = threadIdx.x;
    const int lane = t & 63;
    const int wv = t >> 6;
    for (int i = t; i < 64 * 64; i += 256) {
        Ws[i >> 6][i & 63] = W[i];
        acc[i >> 6][i & 63] = 0.0f;
    }
    if (t < 64) bs[t] = bias[t];
    __syncthreads();

    const int b = blockIdx.x;
    const int s0 = hoff[b * HB];
    const int s1 = (b + 1 < NBUK) ? hoff[(b + 1) * HB] : NE;
    constexpr float WSCL = 1.0f / 32767.0f;
    for (int i = s0 + wv; i < s1; i += 4) {
        const int2 m = edges8[i];                       // wave-uniform 8B load
        const int c = m.x & 0x1FFFF;
        const float wgt = (float)((unsigned)m.x >> 17) * WSCL * dinvg[c];
        const int r6 = m.y & 63;
        atomicAdd(&acc[r6][lane], wgt * x[(size_t)c * D + lane]);  // ds_add_f32
    }
    __syncthreads();

    const int rem = NN - b * 64;
    const int lim = rem < 64 ? rem : 64;    // last bucket has 32 nodes
    for (int i = 0; i < lim; ++i) {
        const int n = b * 64 + i;
        const float dn = dinvg[n];
        float s = 0.0f;
        #pragma unroll
        for (int k = 0; k < 64; k += 4) {
            const float4 a4 = *reinterpret_cast<const float4*>(&acc[i][k]);   // broadcast
            const float4 w4 = *reinterpret_cast<const float4*>(&Ws[lane][k]); // conflict-free
            s += a4.x * w4.x + a4.y * w4.y + a4.z * w4.z + a4.w * w4.w;
        }
        out[(size_t)n * D + lane] = bs[lane] + dn * s;
    }
}

extern "C" void kernel_launch(void* const* d_in, const int* in_sizes, int n_in,
                              void* d_out, int out_size, void* d_ws, size_t ws_size,
                              hipStream_t stream) {
    const float* x    = (const float*)d_in[0];
    const int*   ei   = (const int*)d_in[1];
    const float* dist = (const float*)d_in[2];
    const float* W    = (const float*)d_in[3];
    const float* b    = (const float*)d_in[4];
    float* out = (float*)d_out;

    const int* row = ei;
    const int* col = ei + NE;

    // workspace (~17 MB)
    int2* edges8 = (int2*)d_ws;                        // NE int2 (12.8 MB)
    int*  histT  = (int*)(edges8 + NE);                // NSC (1.6 MB)
    int*  hoff   = histT + NSC;                        // NSC (1.6 MB)
    int*  colcnt = hoff + NSC;                         // NN
    float* dinv  = (float*)(colcnt + NN);              // NN
    int*  bsum   = (int*)(dinv + NN);                  // SCG
    int*  boff   = bsum + SCG;                         // SCG

    hipMemsetAsync(colcnt, 0, (size_t)NN * sizeof(int), stream);

    hist_kernel<<<HB, HT, 0, stream>>>(row, col, colcnt, histT);
    scanpart_kernel<<<SCG, SCB, 0, stream>>>(histT, bsum);
    scanblk_kernel<<<1, 512, 0, stream>>>(bsum, boff);
    scanfinal_kernel<<<SCG, SCB, 0, stream>>>(histT, boff, hoff);
    scatter1_kernel<<<HB, HT, 0, stream>>>(row, col, dist, hoff, edges8);
    dinv_kernel<<<(NN + 255) / 256, 256, 0, stream>>>(colcnt, dinv);
    gather_acc_kernel<<<NBUK, 256, 0, stream>>>(hoff, edges8, dinv, x, W, b, out);
}

// Round 7
// 713.162 us; speedup vs baseline: 1.1638x; 1.1638x over previous
//
#include <hip/hip_runtime.h>

// Geo_GCN via MSD bucket sort (bucket = row>>6 = one 64-node output tile).
// Random memory-side writes minimized to the irreducible 1.6M colcnt atomics.
// Gather: one block per bucket, 8 waves x 8 edges in flight, LDS accumulator,
// fused @W^T + b epilogue. dinv[col] folded into the packed weight at sort time.

constexpr int NN   = 100000;
constexpr int NE   = 1600000;
constexpr int D    = 64;
constexpr int NBUK = (NN + 63) / 64;        // 1563 buckets of 64 nodes
constexpr int HB   = 256;                   // hist/scatter grid
constexpr int HT   = 1024;                  // hist/scatter block
constexpr int CHUNK = NE / HB;              // 6250 edges/block (exact)
constexpr int NSC  = NBUK * HB;             // 400128 scan elements
constexpr int SCB  = 1024;
constexpr int SCG  = (NSC + SCB - 1) / SCB; // 391 scan blocks

// ---- pass 1: bucket histogram (LDS) + colcnt (global atomics, the floor) ----
__global__ void __launch_bounds__(HT)
hist_kernel(const int* __restrict__ row, const int* __restrict__ col,
            int* __restrict__ colcnt, int* __restrict__ histT) {
    __shared__ int h[NBUK];
    const int t = threadIdx.x;
    for (int i = t; i < NBUK; i += HT) h[i] = 0;
    __syncthreads();
    const int e0 = blockIdx.x * CHUNK;
    for (int e = e0 + t; e < e0 + CHUNK; e += HT) {
        atomicAdd(&h[row[e] >> 6], 1);      // LDS, cheap
        atomicAdd(&colcnt[col[e]], 1);      // global, irreducible
    }
    __syncthreads();
    for (int i = t; i < NBUK; i += HT) histT[i * HB + blockIdx.x] = h[i];
}

// ---- dinv = colcnt^{-1/2} (before scatter1, so weight can fold dinv[c]) ----
__global__ void dinv_kernel(const int* __restrict__ colcnt, float* __restrict__ dinv) {
    int i = blockIdx.x * blockDim.x + threadIdx.x;
    if (i < NN) {
        const int d = colcnt[i];
        dinv[i] = (d > 0) ? rsqrtf((float)d) : 0.0f;
    }
}

// ---- scan over histT[NSC] (flat (bucket,block) order) ----
__global__ void scanpart_kernel(const int* __restrict__ a, int* __restrict__ bsum) {
    __shared__ int red[16];
    const int t = threadIdx.x;
    const int i = blockIdx.x * SCB + t;
    int v = (i < NSC) ? a[i] : 0;
    int s = v;
    #pragma unroll
    for (int o = 1; o < 64; o <<= 1) s += __shfl_xor(s, o);
    if ((t & 63) == 0) red[t >> 6] = s;
    __syncthreads();
    if (t < 16) {
        int ss = red[t];
        #pragma unroll
        for (int o = 1; o < 16; o <<= 1) ss += __shfl_xor(ss, o);
        if (t == 0) bsum[blockIdx.x] = ss;
    }
}

__global__ void scanblk_kernel(const int* __restrict__ bsum, int* __restrict__ boff) {
    __shared__ int wsum[8], wsum2[8];
    const int t = threadIdx.x;          // 512
    const int lane = t & 63;
    const int w = t >> 6;               // 0..7
    const int v = (t < SCG) ? bsum[t] : 0;
    int s = v;
    #pragma unroll
    for (int o = 1; o < 64; o <<= 1) { int u = __shfl_up(s, o); if (lane >= o) s += u; }
    if (lane == 63) wsum[w] = s;
    __syncthreads();
    if (t < 8) {
        int ss = wsum[t];
        #pragma unroll
        for (int o = 1; o < 8; o <<= 1) { int u = __shfl_up(ss, o); if (t >= o) ss += u; }
        wsum2[t] = ss;
    }
    __syncthreads();
    const int excl = (w ? wsum2[w - 1] : 0) + (s - v);
    if (t < SCG) boff[t] = excl;
}

__global__ void scanfinal_kernel(const int* __restrict__ a, const int* __restrict__ boff,
                                 int* __restrict__ hoff) {
    __shared__ int wsum[16], wsum2[16];
    const int t = threadIdx.x;
    const int i = blockIdx.x * SCB + t;
    const int lane = t & 63;
    const int w = t >> 6;
    const int v = (i < NSC) ? a[i] : 0;
    int s = v;
    #pragma unroll
    for (int o = 1; o < 64; o <<= 1) { int u = __shfl_up(s, o); if (lane >= o) s += u; }
    if (lane == 63) wsum[w] = s;
    __syncthreads();
    if (t < 16) {
        int ss = wsum[t];
        #pragma unroll
        for (int o = 1; o < 16; o <<= 1) { int u = __shfl_up(ss, o); if (t >= o) ss += u; }
        wsum2[t] = ss;
    }
    __syncthreads();
    const int excl = boff[blockIdx.x] + (w ? wsum2[w - 1] : 0) + (s - v);
    if (i < NSC) hoff[i] = excl;
}

// ---- pass 2: place edges into buckets via LDS cursors (no global atomics) ----
// Weight packed as 15-bit fixed point of exp(-d^2)*dinv[col]  (<= 1).
__global__ void __launch_bounds__(HT)
scatter1_kernel(const int* __restrict__ row, const int* __restrict__ col,
                const float* __restrict__ dist, const float* __restrict__ dinv,
                const int* __restrict__ hoff, int2* __restrict__ edges8) {
    __shared__ int cur[NBUK];
    const int t = threadIdx.x;
    for (int i = t; i < NBUK; i += HT) cur[i] = hoff[i * HB + blockIdx.x];
    __syncthreads();
    const int e0 = blockIdx.x * CHUNK;
    for (int e = e0 + t; e < e0 + CHUNK; e += HT) {
        const int r = row[e];
        const int c = col[e];
        const float dv = dist[e];
        const float wv = expf(-dv * dv) * dinv[c];               // (0, 1]
        const unsigned w15 = (unsigned)(wv * 32767.0f + 0.5f);   // 15-bit fixed pt
        const int pos = atomicAdd(&cur[r >> 6], 1);              // LDS atomic
        edges8[pos] = make_int2((int)((w15 << 17) | (unsigned)c), r);
    }
}

// ---- pass 3: per-bucket gather into LDS accumulator + fused epilogue GEMM ----
// 512 threads = 8 waves; each wave has 8 edges in flight (sub = lane>>3, 8
// channels/lane as 2x float4) -> 64 concurrent gather chains per block.
// acc padded to 68 floats/row: 16B-aligned rows, LDS-atomic banks spread by
// (4*r6 + ch) so random r6 decorrelates banks across subs.
__global__ void __launch_bounds__(512)
gather_acc_kernel(const int* __restrict__ hoff, const int2* __restrict__ edges8,
                  const float* __restrict__ dinvg, const float* __restrict__ x,
                  const float* __restrict__ W, const float* __restrict__ bias,
                  float* __restrict__ out) {
    __shared__ float acc[64][68];   // 17.4KB accumulator (node x channel, padded)
    __shared__ float Ws[64][68];    // W rows, padded
    __shared__ float bs[64];
    const int t = threadIdx.x;
    const int lane = t & 63;
    const int wv = t >> 6;            // 0..7
    const int sub = lane >> 3;        // which of 8 concurrent edges
    const int ch8 = (lane & 7) << 3;  // channel base (8 floats per lane)
    for (int i = t; i < 64 * 64; i += 512) {
        Ws[i >> 6][i & 63] = W[i];
        acc[i >> 6][i & 63] = 0.0f;
    }
    if (t < 64) bs[t] = bias[t];
    __syncthreads();

    const int b = blockIdx.x;
    const int s0 = hoff[b * HB];
    const int s1 = (b + 1 < NBUK) ? hoff[(b + 1) * HB] : NE;
    constexpr float WSCL = 1.0f / 32767.0f;
    for (int i0 = s0 + wv * 8; i0 < s1; i0 += 64) {
        const int ii = i0 + sub;
        const int iic = (ii < s1) ? ii : (s1 - 1);      // clamped -> valid load
        const int2 m = edges8[iic];
        const int c = m.x & 0x1FFFF;
        float wgt = (float)((unsigned)m.x >> 17) * WSCL;
        wgt = (ii < s1) ? wgt : 0.0f;
        const int r6 = m.y & 63;
        const float* xp = x + (size_t)c * D + ch8;
        const float4 xv0 = *reinterpret_cast<const float4*>(xp);
        const float4 xv1 = *reinterpret_cast<const float4*>(xp + 4);
        atomicAdd(&acc[r6][ch8 + 0], wgt * xv0.x);
        atomicAdd(&acc[r6][ch8 + 1], wgt * xv0.y);
        atomicAdd(&acc[r6][ch8 + 2], wgt * xv0.z);
        atomicAdd(&acc[r6][ch8 + 3], wgt * xv0.w);
        atomicAdd(&acc[r6][ch8 + 4], wgt * xv1.x);
        atomicAdd(&acc[r6][ch8 + 5], wgt * xv1.y);
        atomicAdd(&acc[r6][ch8 + 6], wgt * xv1.z);
        atomicAdd(&acc[r6][ch8 + 7], wgt * xv1.w);
    }
    __syncthreads();

    const int rem = NN - b * 64;
    const int lim = rem < 64 ? rem : 64;    // last bucket has 32 nodes
    for (int i = wv; i < lim; i += 8) {
        const int n = b * 64 + i;
        const float dn = dinvg[n];
        float s = 0.0f;
        #pragma unroll
        for (int k = 0; k < 64; k += 4) {
            const float4 a4 = *reinterpret_cast<const float4*>(&acc[i][k]);   // broadcast
            const float4 w4 = *reinterpret_cast<const float4*>(&Ws[lane][k]); // conflict-free
            s += a4.x * w4.x + a4.y * w4.y + a4.z * w4.z + a4.w * w4.w;
        }
        out[(size_t)n * D + lane] = bs[lane] + dn * s;
    }
}

extern "C" void kernel_launch(void* const* d_in, const int* in_sizes, int n_in,
                              void* d_out, int out_size, void* d_ws, size_t ws_size,
                              hipStream_t stream) {
    const float* x    = (const float*)d_in[0];
    const int*   ei   = (const int*)d_in[1];
    const float* dist = (const float*)d_in[2];
    const float* W    = (const float*)d_in[3];
    const float* b    = (const float*)d_in[4];
    float* out = (float*)d_out;

    const int* row = ei;
    const int* col = ei + NE;

    // workspace (~17 MB)
    int2* edges8 = (int2*)d_ws;                        // NE int2 (12.8 MB)
    int*  histT  = (int*)(edges8 + NE);                // NSC (1.6 MB)
    int*  hoff   = histT + NSC;                        // NSC (1.6 MB)
    int*  colcnt = hoff + NSC;                         // NN
    float* dinv  = (float*)(colcnt + NN);              // NN
    int*  bsum   = (int*)(dinv + NN);                  // SCG
    int*  boff   = bsum + SCG;                         // SCG

    hipMemsetAsync(colcnt, 0, (size_t)NN * sizeof(int), stream);

    hist_kernel<<<HB, HT, 0, stream>>>(row, col, colcnt, histT);
    dinv_kernel<<<(NN + 255) / 256, 256, 0, stream>>>(colcnt, dinv);
    scanpart_kernel<<<SCG, SCB, 0, stream>>>(histT, bsum);
    scanblk_kernel<<<1, 512, 0, stream>>>(bsum, boff);
    scanfinal_kernel<<<SCG, SCB, 0, stream>>>(histT, boff, hoff);
    scatter1_kernel<<<HB, HT, 0, stream>>>(row, col, dist, dinv, hoff, edges8);
    gather_acc_kernel<<<NBUK, 512, 0, stream>>>(hoff, edges8, dinv, x, W, b, out);
}

// Round 8
// 166.454 us; speedup vs baseline: 4.9862x; 4.2844x over previous
//
#include <hip/hip_runtime.h>

// Geo_GCN, zero-global-atomic pipeline:
//   hist2 (LDS hists of row>>6, col>>6) -> combined scan ->
//   scatcol (col digits to buckets) -> coldinv (exact deg -> dinv) ->
//   scatter1 (edges to row-buckets, dinv[c] folded into 15-bit weight) ->
//   sort2 (per-bucket counting sort by r&63 -> node-grouped edges + rowstart) ->
//   gather (per-node register accumulation, 8 edges in flight/wave, fused @W^T+b)

constexpr int NN   = 100000;
constexpr int NE   = 1600000;
constexpr int D    = 64;
constexpr int NBUK = (NN + 63) / 64;          // 1563 buckets of 64 nodes
constexpr int HB   = 256;                     // chunk-parallel grid
constexpr int HT   = 1024;
constexpr int CHUNK = NE / HB;                // 6250 (exact)
constexpr int NSC  = NBUK * HB;               // 400128 per hist
constexpr int NSC2 = 2 * NSC;                 // row + col hists, one scan
constexpr int SCB  = 1024;
constexpr int SCG  = (NSC2 + SCB - 1) / SCB;  // 782

// ---- pass 1: both bucket histograms in LDS; no global atomics ----
__global__ void __launch_bounds__(HT)
hist2_kernel(const int* __restrict__ row, const int* __restrict__ col,
             int* __restrict__ hist) {
    __shared__ int hr[NBUK], hc[NBUK];
    const int t = threadIdx.x;
    for (int i = t; i < NBUK; i += HT) { hr[i] = 0; hc[i] = 0; }
    __syncthreads();
    const int e0 = blockIdx.x * CHUNK;
    for (int e = e0 + t; e < e0 + CHUNK; e += HT) {
        atomicAdd(&hr[row[e] >> 6], 1);
        atomicAdd(&hc[col[e] >> 6], 1);
    }
    __syncthreads();
    for (int i = t; i < NBUK; i += HT) {
        hist[i * HB + blockIdx.x]       = hr[i];
        hist[NSC + i * HB + blockIdx.x] = hc[i];
    }
}

// ---- combined exclusive scan over hist[NSC2] ----
__global__ void scanpart_kernel(const int* __restrict__ a, int* __restrict__ bsum) {
    __shared__ int red[16];
    const int t = threadIdx.x;
    const int i = blockIdx.x * SCB + t;
    int s = (i < NSC2) ? a[i] : 0;
    #pragma unroll
    for (int o = 1; o < 64; o <<= 1) s += __shfl_xor(s, o);
    if ((t & 63) == 0) red[t >> 6] = s;
    __syncthreads();
    if (t < 16) {
        int ss = red[t];
        #pragma unroll
        for (int o = 1; o < 16; o <<= 1) ss += __shfl_xor(ss, o);
        if (t == 0) bsum[blockIdx.x] = ss;
    }
}

__global__ void scanblk_kernel(const int* __restrict__ bsum, int* __restrict__ boff) {
    __shared__ int wsum[16], wsum2[16];
    const int t = threadIdx.x;              // 1024
    const int lane = t & 63;
    const int w = t >> 6;
    const int v = (t < SCG) ? bsum[t] : 0;
    int s = v;
    #pragma unroll
    for (int o = 1; o < 64; o <<= 1) { int u = __shfl_up(s, o); if (lane >= o) s += u; }
    if (lane == 63) wsum[w] = s;
    __syncthreads();
    if (t < 16) {
        int ss = wsum[t];
        #pragma unroll
        for (int o = 1; o < 16; o <<= 1) { int u = __shfl_up(ss, o); if (t >= o) ss += u; }
        wsum2[t] = ss;
    }
    __syncthreads();
    const int excl = (w ? wsum2[w - 1] : 0) + (s - v);
    if (t < SCG) boff[t] = excl;
}

// in-place: hist -> exclusive offsets (each thread touches only its own element)
__global__ void scanfinal_kernel(int* __restrict__ a, const int* __restrict__ boff) {
    __shared__ int wsum[16], wsum2[16];
    const int t = threadIdx.x;
    const int i = blockIdx.x * SCB + t;
    const int lane = t & 63;
    const int w = t >> 6;
    const int v = (i < NSC2) ? a[i] : 0;
    int s = v;
    #pragma unroll
    for (int o = 1; o < 64; o <<= 1) { int u = __shfl_up(s, o); if (lane >= o) s += u; }
    if (lane == 63) wsum[w] = s;
    __syncthreads();
    if (t < 16) {
        int ss = wsum[t];
        #pragma unroll
        for (int o = 1; o < 16; o <<= 1) { int u = __shfl_up(ss, o); if (t >= o) ss += u; }
        wsum2[t] = ss;
    }
    __syncthreads();
    const int excl = boff[blockIdx.x] + (w ? wsum2[w - 1] : 0) + (s - v);
    if (i < NSC2) a[i] = excl;
}

// ---- col digits into col-buckets (LDS cursors) ----
__global__ void __launch_bounds__(HT)
scatcol_kernel(const int* __restrict__ col, const int* __restrict__ hoff,
               unsigned char* __restrict__ colidx) {
    __shared__ int cur[NBUK];
    const int t = threadIdx.x;
    for (int i = t; i < NBUK; i += HT) cur[i] = hoff[NSC + i * HB + blockIdx.x] - NE;
    __syncthreads();
    const int e0 = blockIdx.x * CHUNK;
    for (int e = e0 + t; e < e0 + CHUNK; e += HT) {
        const int c = col[e];
        const int pos = atomicAdd(&cur[c >> 6], 1);
        colidx[pos] = (unsigned char)(c & 63);
    }
}

// ---- per-bucket exact degree count -> dinv ----
__global__ void __launch_bounds__(256)
coldinv_kernel(const int* __restrict__ hoff, const unsigned char* __restrict__ colidx,
               float* __restrict__ dinv) {
    __shared__ int cnt[64];
    const int t = threadIdx.x;
    const int b = blockIdx.x;
    if (t < 64) cnt[t] = 0;
    __syncthreads();
    const int s0 = hoff[NSC + b * HB] - NE;
    const int s1 = (b + 1 < NBUK) ? (hoff[NSC + (b + 1) * HB] - NE) : NE;
    for (int k = s0 + t; k < s1; k += 256) atomicAdd(&cnt[colidx[k]], 1);
    __syncthreads();
    if (t < 64) {
        const int n = b * 64 + t;
        if (n < NN) {
            const int d = cnt[t];
            dinv[n] = (d > 0) ? rsqrtf((float)d) : 0.0f;
        }
    }
}

// ---- edges into row-buckets; weight = 15-bit fp of exp(-d^2)*dinv[c] ----
__global__ void __launch_bounds__(HT)
scatter1_kernel(const int* __restrict__ row, const int* __restrict__ col,
                const float* __restrict__ dist, const float* __restrict__ dinv,
                const int* __restrict__ hoff, int2* __restrict__ edges8) {
    __shared__ int cur[NBUK];
    const int t = threadIdx.x;
    for (int i = t; i < NBUK; i += HT) cur[i] = hoff[i * HB + blockIdx.x];
    __syncthreads();
    const int e0 = blockIdx.x * CHUNK;
    for (int e = e0 + t; e < e0 + CHUNK; e += HT) {
        const int r = row[e];
        const int c = col[e];
        const float dv = dist[e];
        const float wv = expf(-dv * dv) * dinv[c];               // (0, 1]
        const unsigned w15 = (unsigned)(wv * 32767.0f + 0.5f);
        const int pos = atomicAdd(&cur[r >> 6], 1);              // LDS atomic
        edges8[pos] = make_int2((int)((w15 << 17) | (unsigned)c), r);
    }
}

// ---- per-bucket counting sort by r&63 -> node-grouped 4B edges + rowstart ----
__global__ void __launch_bounds__(256)
sort2_kernel(const int* __restrict__ hoff, const int2* __restrict__ edges8,
             unsigned* __restrict__ edges4, int* __restrict__ rowstart) {
    __shared__ int cnt[64], cur[64];
    const int t = threadIdx.x;
    const int b = blockIdx.x;
    if (t < 64) cnt[t] = 0;
    __syncthreads();
    const int s0 = hoff[b * HB];
    const int s1 = (b + 1 < NBUK) ? hoff[(b + 1) * HB] : NE;
    for (int k = s0 + t; k < s1; k += 256) atomicAdd(&cnt[edges8[k].y & 63], 1);
    __syncthreads();
    if (t < 64) {
        const int v = cnt[t];
        int s = v;
        #pragma unroll
        for (int o = 1; o < 64; o <<= 1) { int u = __shfl_up(s, o); if (t >= o) s += u; }
        const int excl = s - v;
        cur[t] = excl;
        rowstart[b * 64 + t] = s0 + excl;      // start of node b*64+t
        if (b == NBUK - 1 && t == 63) rowstart[NBUK * 64] = NE;
    }
    __syncthreads();
    for (int k = s0 + t; k < s1; k += 256) {
        const int2 m = edges8[k];
        const int pos = s0 + atomicAdd(&cur[m.y & 63], 1);
        edges4[pos] = (unsigned)m.x;
    }
}

// ---- per-node register gather (8 edges in flight/wave) + fused epilogue ----
__global__ void __launch_bounds__(256)
gather_kernel(const int* __restrict__ rowstart, const unsigned* __restrict__ edges4,
              const float* __restrict__ dinvg, const float* __restrict__ x,
              const float* __restrict__ W, const float* __restrict__ bias,
              float* __restrict__ out) {
    __shared__ float Wt[D][D + 1];  // Wt[k][j] = W[j*D+k]
    __shared__ float bs[D];
    __shared__ float srow[4][D];
    const int t = threadIdx.x;
    const int lane = t & 63;
    const int wv = t >> 6;
    const int sub = lane >> 3;        // which of 8 concurrent edges
    const int ch8 = (lane & 7) << 3;  // 8 channels per lane
    constexpr float WSCL = 1.0f / 32767.0f;
    for (int i = t; i < D * D; i += 256) Wt[i & 63][i >> 6] = W[i];
    if (t < D) bs[t] = bias[t];
    __syncthreads();

    const int nwaves = gridDim.x * 4;
    for (int n = blockIdx.x * 4 + wv; n < NN; n += nwaves) {
        const int s0 = rowstart[n];
        const int s1 = rowstart[n + 1];
        float4 a0 = make_float4(0.0f, 0.0f, 0.0f, 0.0f);
        float4 a1 = make_float4(0.0f, 0.0f, 0.0f, 0.0f);
        for (int p0 = s0; p0 < s1; p0 += 8) {
            const int pp = p0 + sub;
            const int ppc = (pp < s1) ? pp : (s1 - 1);    // clamped -> valid load
            const unsigned m = edges4[ppc];
            const int c = (int)(m & 0x1FFFFu);
            float wgt = (float)(m >> 17) * WSCL;
            wgt = (pp < s1) ? wgt : 0.0f;
            const float* xp = x + (size_t)c * D + ch8;
            const float4 xv0 = *reinterpret_cast<const float4*>(xp);
            const float4 xv1 = *reinterpret_cast<const float4*>(xp + 4);
            a0.x += wgt * xv0.x; a0.y += wgt * xv0.y;
            a0.z += wgt * xv0.z; a0.w += wgt * xv0.w;
            a1.x += wgt * xv1.x; a1.y += wgt * xv1.y;
            a1.z += wgt * xv1.z; a1.w += wgt * xv1.w;
        }
        #pragma unroll
        for (int o = 8; o < 64; o <<= 1) {
            a0.x += __shfl_xor(a0.x, o); a0.y += __shfl_xor(a0.y, o);
            a0.z += __shfl_xor(a0.z, o); a0.w += __shfl_xor(a0.w, o);
            a1.x += __shfl_xor(a1.x, o); a1.y += __shfl_xor(a1.y, o);
            a1.z += __shfl_xor(a1.z, o); a1.w += __shfl_xor(a1.w, o);
        }
        if (sub == 0) {
            const float dn = dinvg[n];
            a0.x *= dn; a0.y *= dn; a0.z *= dn; a0.w *= dn;
            a1.x *= dn; a1.y *= dn; a1.z *= dn; a1.w *= dn;
            *reinterpret_cast<float4*>(&srow[wv][ch8]) = a0;
            *reinterpret_cast<float4*>(&srow[wv][ch8 + 4]) = a1;
        }
        float o_ = bs[lane];
        #pragma unroll
        for (int k = 0; k < D; ++k) o_ += srow[wv][k] * Wt[k][lane];
        out[(size_t)n * D + lane] = o_;
    }
}

extern "C" void kernel_launch(void* const* d_in, const int* in_sizes, int n_in,
                              void* d_out, int out_size, void* d_ws, size_t ws_size,
                              hipStream_t stream) {
    const float* x    = (const float*)d_in[0];
    const int*   ei   = (const int*)d_in[1];
    const float* dist = (const float*)d_in[2];
    const float* W    = (const float*)d_in[3];
    const float* b    = (const float*)d_in[4];
    float* out = (float*)d_out;

    const int* row = ei;
    const int* col = ei + NE;

    // workspace (~24.9 MB; 26 MB proven safe in round 1)
    int2*     edges8   = (int2*)d_ws;                       // NE int2 (12.8 MB)
    unsigned* edges4   = (unsigned*)(edges8 + NE);          // NE u32 (6.4 MB)
    int*      hist     = (int*)(edges4 + NE);               // NSC2 (3.2 MB), becomes hoff in place
    int*      rowstart = hist + NSC2;                       // NBUK*64+1 (~400 KB)
    float*    dinv     = (float*)(rowstart + NBUK * 64 + 1);// NN
    int*      bsum     = (int*)(dinv + NN);                 // SCG
    int*      boff     = bsum + SCG;                        // SCG
    unsigned char* colidx = (unsigned char*)(boff + SCG);   // NE bytes (1.6 MB)

    hist2_kernel   <<<HB, HT, 0, stream>>>(row, col, hist);
    scanpart_kernel<<<SCG, SCB, 0, stream>>>(hist, bsum);
    scanblk_kernel <<<1, 1024, 0, stream>>>(bsum, boff);
    scanfinal_kernel<<<SCG, SCB, 0, stream>>>(hist, boff);
    scatcol_kernel <<<HB, HT, 0, stream>>>(col, hist, colidx);
    coldinv_kernel <<<NBUK, 256, 0, stream>>>(hist, colidx, dinv);
    scatter1_kernel<<<HB, HT, 0, stream>>>(row, col, dist, dinv, hist, edges8);
    sort2_kernel   <<<NBUK, 256, 0, stream>>>(hist, edges8, edges4, rowstart);
    gather_kernel  <<<4096, 256, 0, stream>>>(rowstart, edges4, dinv, x, W, b, out);
}